// Round 3
// baseline (1201.620 us; speedup 1.0000x reference)
//
#include <hip/hip_runtime.h>

typedef float f32x4 __attribute__((ext_vector_type(4)));

static constexpr int E_ = 8, M_ = 4096, K_ = 2048, N_ = 2048;
static constexpr int KB_ = 16;           // 128-wide k scale blocks
static constexpr int NB128 = N_ / 128;   // weight n-blocks
static constexpr int BM = 256, BN = 256, BK = 128;
static constexpr int KT = K_ / BK;       // 16 K-tiles
static constexpr int MT2 = M_ / BM;      // 16
static constexpr int NT2 = N_ / BN;      // 8
#define FP8MAX 448.0f

// ---------------- quantize x: one scale per (row, 128-k-block) ----------------
__global__ __launch_bounds__(256) void quant_x_kernel(const float* __restrict__ x,
                                                      unsigned char* __restrict__ qx,
                                                      float* __restrict__ sx) {
  long tile = (long)blockIdx.x * 8 + (threadIdx.x >> 5);
  int lane = threadIdx.x & 31;
  f32x4 v = *(const f32x4*)(x + tile * 128 + lane * 4);
  float am = fmaxf(fmaxf(fabsf(v[0]), fabsf(v[1])), fmaxf(fabsf(v[2]), fabsf(v[3])));
#pragma unroll
  for (int off = 16; off; off >>= 1) am = fmaxf(am, __shfl_xor(am, off, 32));
  float safe = fmaxf(am, 1e-4f);
  float qs = FP8MAX / safe;
  int pk = 0;
  pk = __builtin_amdgcn_cvt_pk_fp8_f32(v[0] * qs, v[1] * qs, pk, false);
  pk = __builtin_amdgcn_cvt_pk_fp8_f32(v[2] * qs, v[3] * qs, pk, true);
  *(int*)(qx + tile * 128 + lane * 4) = pk;
  if (lane == 0) sx[tile] = safe / FP8MAX;
}

// ---------------- quantize w: one scale per 128x128 block ----------------
__global__ __launch_bounds__(256) void quant_w_kernel(const float* __restrict__ w,
                                                      unsigned char* __restrict__ qw,
                                                      float* __restrict__ sw) {
  int b = blockIdx.x;
  int kb = b % KB_;
  int t2 = b / KB_;
  int nb = t2 % NB128;
  int e = t2 / NB128;
  int tid = threadIdx.x;
  int r = tid >> 1;
  int c0 = (tid & 1) * 64;
  const float* base = w + ((long)(e * N_ + nb * 128 + r)) * K_ + kb * 128 + c0;
  f32x4 v[16];
  float am = 0.f;
#pragma unroll
  for (int j = 0; j < 16; ++j) {
    v[j] = *(const f32x4*)(base + j * 4);
    am = fmaxf(am, fmaxf(fmaxf(fabsf(v[j][0]), fabsf(v[j][1])),
                         fmaxf(fabsf(v[j][2]), fabsf(v[j][3]))));
  }
#pragma unroll
  for (int off = 32; off; off >>= 1) am = fmaxf(am, __shfl_xor(am, off, 64));
  __shared__ float red[4];
  if ((tid & 63) == 0) red[tid >> 6] = am;
  __syncthreads();
  am = fmaxf(fmaxf(red[0], red[1]), fmaxf(red[2], red[3]));
  float safe = fmaxf(am, 1e-6f);
  float qs = FP8MAX / safe;
  unsigned char* outp = qw + ((long)(e * N_ + nb * 128 + r)) * K_ + kb * 128 + c0;
#pragma unroll
  for (int j4 = 0; j4 < 4; ++j4) {
    uint4 pkv;
    unsigned int* pp = (unsigned int*)&pkv;
#pragma unroll
    for (int q = 0; q < 4; ++q) {
      int j = j4 * 4 + q;
      int pk = 0;
      pk = __builtin_amdgcn_cvt_pk_fp8_f32(v[j][0] * qs, v[j][1] * qs, pk, false);
      pk = __builtin_amdgcn_cvt_pk_fp8_f32(v[j][2] * qs, v[j][3] * qs, pk, true);
      pp[q] = (unsigned int)pk;
    }
    *(uint4*)(outp + j4 * 16) = pkv;
  }
  if (tid == 0) sw[(e * NB128 + nb) * KB_ + kb] = safe / FP8MAX;
}

// ---------------- grouped GEMM: 256x256 tile, BK=128, 8-phase pipeline ----------------
__device__ inline void gload16(const void* g, void* l) {
  __builtin_amdgcn_global_load_lds(
      (const __attribute__((address_space(1))) unsigned int*)g,
      (__attribute__((address_space(3))) unsigned int*)l, 16, 0, 0);
}

#define BAR __builtin_amdgcn_s_barrier()

#define LOAD_A(MFH)                                                             \
  _Pragma("unroll") for (int mf = 0; mf < 4; ++mf) {                            \
    _Pragma("unroll") for (int ks = 0; ks < 4; ++ks)                            \
      af[mf][ks] = *(const long*)&Acur[(arow0 + (MFH) * 64 + mf * 16) * BK +    \
                                       cofs[ks]];                               \
  }

#define LOAD_B(NF0)                                                             \
  _Pragma("unroll") for (int nf2 = 0; nf2 < 2; ++nf2) {                         \
    _Pragma("unroll") for (int ks = 0; ks < 4; ++ks)                            \
      bf[(NF0) + nf2][ks] =                                                     \
          *(const long*)&Bcur[(brow0 + ((NF0) + nf2) * 16) * BK + cofs[ks]];    \
  }

#define LOAD_SXW(MFH)                                                           \
  _Pragma("unroll") for (int mf = 0; mf < 4; ++mf)                              \
      sxw[mf] = (*(const f32x4*)&sxl[kt][wr * 128 + (MFH) * 64 + mf * 16 +      \
                                         qq * 4]) * swk;

#define MFMA_FOLD(MFH, NF0)                                                     \
  do {                                                                          \
    __builtin_amdgcn_s_setprio(1);                                              \
    _Pragma("unroll") for (int mf = 0; mf < 4; ++mf) {                          \
      _Pragma("unroll") for (int nf2 = 0; nf2 < 2; ++nf2) {                     \
        f32x4 p = {0.f, 0.f, 0.f, 0.f};                                         \
        _Pragma("unroll") for (int ks = 0; ks < 4; ++ks)                        \
            p = __builtin_amdgcn_mfma_f32_16x16x32_fp8_fp8(                     \
                af[mf][ks], bf[(NF0) + nf2][ks], p, 0, 0, 0);                   \
        _Pragma("unroll") for (int r = 0; r < 4; ++r)                           \
            acc[(MFH) * 4 + mf][(NF0) + nf2][r] += p[r] * sxw[mf][r];           \
      }                                                                         \
    }                                                                           \
    __builtin_amdgcn_s_setprio(0);                                              \
  } while (0)

__global__ __launch_bounds__(512, 2) void gemm_kernel(
    const unsigned char* __restrict__ qx, const unsigned char* __restrict__ qw,
    const float* __restrict__ sx, const float* __restrict__ sw,
    float* __restrict__ out) {
  __shared__ unsigned char As[2][BM * BK];   // 64 KiB
  __shared__ unsigned char Bs[2][BN * BK];   // 64 KiB
  __shared__ float sxl[KT][BM];              // 16 KiB, [kb][row]
  __shared__ float swl[2][KT];

  const int e = blockIdx.y;
  const int x = blockIdx.x;
  const int swz = (x & 7) * 16 + (x >> 3);   // XCD-contiguous chunks (128 % 8 == 0)
  const int mt = swz >> 3, nt = swz & 7;
  const int brow = mt * BM, bcol = nt * BN;

  const int tid = threadIdx.x;
  const int w = tid >> 6, l = tid & 63;
  const int wr = w >> 2, wc = w & 3;         // 2 (M) x 4 (N) waves; 128x64 C each
  const int qq = l >> 4, rl = l & 15;
  const int o8 = (qq & 1) * 8, ch = qq >> 1;
  const int rx = rl & 7;

  const unsigned char* Ab = qx + (size_t)(e * M_ + brow) * K_;
  const unsigned char* Bb = qw + (size_t)(e * N_ + bcol) * K_;

  // ---- stage dequant scales into LDS ----
  {
    int row = tid >> 1, h = (tid & 1) * 8;
    const float* sp = sx + (size_t)(e * M_ + brow + row) * KB_ + h;
    f32x4 s0 = *(const f32x4*)sp;
    f32x4 s1 = *(const f32x4*)(sp + 4);
#pragma unroll
    for (int j = 0; j < 4; ++j) {
      sxl[h + j][row] = s0[j];
      sxl[h + 4 + j][row] = s1[j];
    }
    if (tid < 32)
      swl[tid >> 4][tid & 15] =
          sw[(e * NB128 + nt * 2 + (tid >> 4)) * KB_ + (tid & 15)];
  }
  __syncthreads();   // scales visible before the K-loop reads them

  // ---- staging helpers: 1 unit = 64 rows x 128B = one gload16 per thread ----
  const int c8 = l & 7, r8 = (l >> 3) & 7;
  const int srcswz = (c8 ^ r8) * 16;     // pre-swizzled global chunk, linear LDS
  auto stageA = [&](int rowbase, int kt2, int tb) {
    gload16(Ab + (size_t)(rowbase + w * 8 + (l >> 3)) * K_ + kt2 * BK + srcswz,
            &As[tb][(rowbase + w * 8) * BK]);
  };
  auto stageB = [&](int rowbase0, int kt2, int tb) {   // rowbase0: 0,128,32,160
    int rb = rowbase0 + (w & 3) * 8 + (w >> 2) * 64;
    gload16(Bb + (size_t)(rb + (l >> 3)) * K_ + kt2 * BK + srcswz,
            &Bs[tb][rb * BK]);
  };

  // ---- prologue: fully stage tiles 0 and 1, then PUBLISH tile 0 ----
#pragma unroll
  for (int t = 0; t < 2; ++t) {
    stageA(0, t, t); stageA(128, t, t); stageA(64, t, t); stageA(192, t, t);
    stageB(0, t, t); stageB(128, t, t); stageB(32, t, t); stageB(160, t, t);
  }
  // drain own tile-0 loads (8 newest = tile 1's), then barrier so ALL waves'
  // tile-0 data is in LDS before anyone reads it.
  asm volatile("s_waitcnt vmcnt(8)" ::: "memory");
  BAR;
  __builtin_amdgcn_sched_barrier(0);

  f32x4 acc[8][4] = {};
  long af[4][4], bf[4][4];
  f32x4 sxw[4];
  int cofs[4];
#pragma unroll
  for (int ks = 0; ks < 4; ++ks) cofs[ks] = (((2 * ks + ch) ^ rx) * 16) + o8;
  const int arow0 = wr * 128 + rl;
  const int brow0 = wc * 64 + rl;

  for (int kt = 0; kt < KT; ++kt) {
    const int buf = kt & 1;
    const unsigned char* Acur = As[buf];
    const unsigned char* Bcur = Bs[buf];
    const float swk = swl[wc >> 1][kt];

    // phase 0: (mf-lo, nf 0-1) — tile kt published by previous iteration's BAR
    LOAD_A(0); LOAD_B(0); LOAD_SXW(0);
    BAR;
    MFMA_FOLD(0, 0);
    BAR;
    // phase 1: (mf-lo, nf 2-3); A-lo rows consumed -> stage kt+2 there
    if (kt + 2 < KT) { stageA(0, kt + 2, buf); stageA(128, kt + 2, buf); }
    LOAD_B(2);
    BAR;
    MFMA_FOLD(0, 2);
    BAR;
    // phase 2: (mf-hi, nf 0-1); B-lo rows consumed
    if (kt + 2 < KT) { stageB(0, kt + 2, buf); stageB(128, kt + 2, buf); }
    LOAD_A(1); LOAD_SXW(1);
    BAR;
    MFMA_FOLD(1, 0);
    BAR;
    // phase 3: (mf-hi, nf 2-3); B-hi + A-hi rows consumed
    if (kt + 2 < KT) { stageB(32, kt + 2, buf); stageB(160, kt + 2, buf);
                       stageA(64, kt + 2, buf); stageA(192, kt + 2, buf); }
    BAR;
    MFMA_FOLD(1, 2);
    // ---- publish tile kt+1: drain OWN loads, THEN barrier (drain-then-publish)
    // outstanding: tile kt+1's 8 (oldest) + tile kt+2's 8 (if staged this iter)
    if (kt < KT - 2)       { asm volatile("s_waitcnt vmcnt(8)" ::: "memory"); }
    else if (kt == KT - 2) { asm volatile("s_waitcnt vmcnt(0)" ::: "memory"); }
    BAR;
    __builtin_amdgcn_sched_barrier(0);
  }

  // ---- epilogue: C row = qq*4 + r, col = rl (validated round 1) ----
#pragma unroll
  for (int MF = 0; MF < 8; ++MF) {
    const int m = brow + wr * 128 + MF * 16 + qq * 4;
#pragma unroll
    for (int nf = 0; nf < 4; ++nf) {
      const int n = bcol + wc * 64 + nf * 16 + rl;
      float* op = out + (size_t)(e * M_ + m) * N_ + n;
#pragma unroll
      for (int r = 0; r < 4; ++r) op[(size_t)r * N_] = acc[MF][nf][r];
    }
  }
}

extern "C" void kernel_launch(void* const* d_in, const int* in_sizes, int n_in,
                              void* d_out, int out_size, void* d_ws, size_t ws_size,
                              hipStream_t stream) {
  const float* x = (const float*)d_in[0];
  const float* wt = (const float*)d_in[1];
  float* out = (float*)d_out;

  unsigned char* ws = (unsigned char*)d_ws;
  unsigned char* qx = ws;                               // 64 MiB
  unsigned char* qw = ws + (size_t)E_ * M_ * K_;        // 32 MiB
  float* sx = (float*)(qw + (size_t)E_ * N_ * K_);      // 2 MiB
  float* sw = sx + (size_t)E_ * M_ * KB_;               // 8 KiB

  quant_x_kernel<<<dim3((E_ * M_ * KB_) / 8), dim3(256), 0, stream>>>(x, qx, sx);
  quant_w_kernel<<<dim3(E_ * NB128 * KB_), dim3(256), 0, stream>>>(wt, qw, sw);
  gemm_kernel<<<dim3(MT2 * NT2, E_), dim3(512), 0, stream>>>(qx, qw, sx, sw, out);
}

// Round 4
// 466.604 us; speedup vs baseline: 2.5752x; 2.5752x over previous
//
#include <hip/hip_runtime.h>

typedef float f32x4 __attribute__((ext_vector_type(4)));
typedef float f32x16 __attribute__((ext_vector_type(16)));

static constexpr int E_ = 8, M_ = 4096, K_ = 2048, N_ = 2048;
static constexpr int KB_ = 16;           // 128-wide k scale blocks
static constexpr int NB128 = N_ / 128;   // weight n-blocks
static constexpr int BM = 256, BN = 128, BK = 128;
static constexpr int KT = K_ / BK;       // 16 K-tiles
static constexpr int MT2 = M_ / BM;      // 16
static constexpr int NT2 = N_ / BN;      // 16
#define FP8MAX 448.0f

// ---------------- quantize x: one scale per (row, 128-k-block) ----------------
__global__ __launch_bounds__(256) void quant_x_kernel(const float* __restrict__ x,
                                                      unsigned char* __restrict__ qx,
                                                      float* __restrict__ sx) {
  long tile = (long)blockIdx.x * 8 + (threadIdx.x >> 5);
  int lane = threadIdx.x & 31;
  f32x4 v = *(const f32x4*)(x + tile * 128 + lane * 4);
  float am = fmaxf(fmaxf(fabsf(v[0]), fabsf(v[1])), fmaxf(fabsf(v[2]), fabsf(v[3])));
#pragma unroll
  for (int off = 16; off; off >>= 1) am = fmaxf(am, __shfl_xor(am, off, 32));
  float safe = fmaxf(am, 1e-4f);
  float qs = FP8MAX / safe;
  int pk = 0;
  pk = __builtin_amdgcn_cvt_pk_fp8_f32(v[0] * qs, v[1] * qs, pk, false);
  pk = __builtin_amdgcn_cvt_pk_fp8_f32(v[2] * qs, v[3] * qs, pk, true);
  *(int*)(qx + tile * 128 + lane * 4) = pk;
  if (lane == 0) sx[tile] = safe / FP8MAX;
}

// ---------------- quantize w: one scale per 128x128 block ----------------
__global__ __launch_bounds__(256) void quant_w_kernel(const float* __restrict__ w,
                                                      unsigned char* __restrict__ qw,
                                                      float* __restrict__ sw) {
  int b = blockIdx.x;
  int kb = b % KB_;
  int t2 = b / KB_;
  int nb = t2 % NB128;
  int e = t2 / NB128;
  int tid = threadIdx.x;
  int r = tid >> 1;
  int c0 = (tid & 1) * 64;
  const float* base = w + ((long)(e * N_ + nb * 128 + r)) * K_ + kb * 128 + c0;
  f32x4 v[16];
  float am = 0.f;
#pragma unroll
  for (int j = 0; j < 16; ++j) {
    v[j] = *(const f32x4*)(base + j * 4);
    am = fmaxf(am, fmaxf(fmaxf(fabsf(v[j][0]), fabsf(v[j][1])),
                         fmaxf(fabsf(v[j][2]), fabsf(v[j][3]))));
  }
#pragma unroll
  for (int off = 32; off; off >>= 1) am = fmaxf(am, __shfl_xor(am, off, 64));
  __shared__ float red[4];
  if ((tid & 63) == 0) red[tid >> 6] = am;
  __syncthreads();
  am = fmaxf(fmaxf(red[0], red[1]), fmaxf(red[2], red[3]));
  float safe = fmaxf(am, 1e-6f);
  float qs = FP8MAX / safe;
  unsigned char* outp = qw + ((long)(e * N_ + nb * 128 + r)) * K_ + kb * 128 + c0;
#pragma unroll
  for (int j4 = 0; j4 < 4; ++j4) {
    uint4 pkv;
    unsigned int* pp = (unsigned int*)&pkv;
#pragma unroll
    for (int q = 0; q < 4; ++q) {
      int j = j4 * 4 + q;
      int pk = 0;
      pk = __builtin_amdgcn_cvt_pk_fp8_f32(v[j][0] * qs, v[j][1] * qs, pk, false);
      pk = __builtin_amdgcn_cvt_pk_fp8_f32(v[j][2] * qs, v[j][3] * qs, pk, true);
      pp[q] = (unsigned int)pk;
    }
    *(uint4*)(outp + j4 * 16) = pkv;
  }
  if (tid == 0) sw[(e * NB128 + nb) * KB_ + kb] = safe / FP8MAX;
}

// ---------------- grouped GEMM: 256x128 tile, 32x32x16 MFMA, 4-phase pipeline --------
__device__ inline void gload16(const void* g, void* l) {
  __builtin_amdgcn_global_load_lds(
      (const __attribute__((address_space(1))) unsigned int*)g,
      (__attribute__((address_space(3))) unsigned int*)l, 16, 0, 0);
}

#define BAR __builtin_amdgcn_s_barrier()

// 8-deep chained 32x32x16 MFMA + one f32x16 scale-fold
#define MMACC(ACC, AV, BV, SXV)                                                 \
  do {                                                                          \
    f32x16 p = {0.f, 0.f, 0.f, 0.f, 0.f, 0.f, 0.f, 0.f,                        \
                0.f, 0.f, 0.f, 0.f, 0.f, 0.f, 0.f, 0.f};                        \
    __builtin_amdgcn_s_setprio(1);                                              \
    _Pragma("unroll") for (int ks = 0; ks < 8; ++ks)                            \
        p = __builtin_amdgcn_mfma_f32_32x32x16_fp8_fp8(AV[ks], BV[ks], p, 0, 0, 0); \
    __builtin_amdgcn_s_setprio(0);                                              \
    ACC += p * (SXV);                                                           \
  } while (0)

// x-scale vector for one 32-row block: s[r] = sx[row=(r&3)+8*(r>>2)+4*hi] * swk
#define LDSX(SV, MB)                                                            \
  do {                                                                          \
    _Pragma("unroll") for (int g = 0; g < 4; ++g) {                             \
      f32x4 t = *(const f32x4*)&sxl[kt][wr * 64 + (MB) * 32 + hi * 4 + g * 8];  \
      _Pragma("unroll") for (int j = 0; j < 4; ++j) SV[g * 4 + j] = t[j] * swk; \
    }                                                                           \
  } while (0)

__global__ __launch_bounds__(512, 2) void gemm_kernel(
    const unsigned char* __restrict__ qx, const unsigned char* __restrict__ qw,
    const float* __restrict__ sx, const float* __restrict__ sw,
    float* __restrict__ out) {
  __shared__ unsigned char As[2][BM * BK];   // 64 KiB
  __shared__ unsigned char Bs[2][BN * BK];   // 32 KiB
  __shared__ float sxl[KT][BM];              // 16 KiB
  __shared__ float swl[KT];

  const int e = blockIdx.y;
  const int x = blockIdx.x;
  const int swz = (x & 7) * 32 + (x >> 3);   // bijective: 256 % 8 == 0
  const int mt = swz >> 4, nt = swz & 15;
  const int brow = mt * BM, bcol = nt * BN;

  const int tid = threadIdx.x;
  const int w = tid >> 6, l = tid & 63;
  const int wr = w >> 1, wc = w & 1;         // 4 (M) x 2 (N) waves; 64x64 C each
  const int r32 = l & 31, hi = l >> 5, rx = l & 7;

  const unsigned char* Ab = qx + (size_t)(e * M_ + brow) * K_;
  const unsigned char* Bb = qw + (size_t)(e * N_ + bcol) * K_;

  // ---- stage dequant scales ----
  {
    int row = tid >> 1, h = (tid & 1) * 8;
    const float* sp = sx + (size_t)(e * M_ + brow + row) * KB_ + h;
    f32x4 s0 = *(const f32x4*)sp;
    f32x4 s1 = *(const f32x4*)(sp + 4);
#pragma unroll
    for (int j = 0; j < 4; ++j) {
      sxl[h + j][row] = s0[j];
      sxl[h + 4 + j][row] = s1[j];
    }
    if (tid < KT) swl[tid] = sw[(e * NB128 + nt) * KB_ + tid];
  }
  __syncthreads();

  // ---- staging: unit = 64 rows x 128B; per wave an 8-row strip, linear LDS ----
  const int c8 = l & 7, r8 = (l >> 3) & 7;
  const int srcswz = (c8 ^ r8) * 16;         // LDS chunk c of row r holds global chunk c^(r&7)
  auto stageA = [&](int rowbase, int kt2, int tb) {
    gload16(Ab + (size_t)(rowbase + w * 8 + (l >> 3)) * K_ + kt2 * BK + srcswz,
            &As[tb][(rowbase + w * 8) * BK]);
  };
  auto stageB = [&](int rowbase, int kt2, int tb) {
    gload16(Bb + (size_t)(rowbase + w * 8 + (l >> 3)) * K_ + kt2 * BK + srcswz,
            &Bs[tb][(rowbase + w * 8) * BK]);
  };

  // ---- prologue: stage tiles 0,1 (6 loads each); publish tile 0 ----
#pragma unroll
  for (int t = 0; t < 2; ++t) {
    stageA(0, t, t); stageA(64, t, t); stageA(128, t, t); stageA(192, t, t);
    stageB(0, t, t); stageB(64, t, t);
  }
  asm volatile("s_waitcnt vmcnt(6)" ::: "memory");   // tile 0 landed; tile 1 in flight
  BAR;
  __builtin_amdgcn_sched_barrier(0);

  f32x16 acc00 = {0.f}, acc01 = {0.f}, acc10 = {0.f}, acc11 = {0.f};
  int cofs[8];
#pragma unroll
  for (int ks = 0; ks < 8; ++ks) cofs[ks] = ((ks ^ rx) * 16) + hi * 8;
  const int arow_b = (wr * 64 + r32) * BK;   // mb adds 32*BK (row&7 unchanged)
  const int brow_b = (wc * 64 + r32) * BK;

  long a0[8], a1[8], b0[8], b1[8];
  f32x16 sx0, sx1;

  for (int kt = 0; kt < KT; ++kt) {
    const int buf = kt & 1;
    const unsigned char* Acur = As[buf];
    const unsigned char* Bcur = Bs[buf];
    const float swk = swl[kt];

    // phase 0: quadrant (0,0)
    LDSX(sx0, 0);
#pragma unroll
    for (int ks = 0; ks < 8; ++ks) a0[ks] = *(const long*)&Acur[arow_b + cofs[ks]];
#pragma unroll
    for (int ks = 0; ks < 8; ++ks) b0[ks] = *(const long*)&Bcur[brow_b + cofs[ks]];
    BAR;
    MMACC(acc00, a0, b0, sx0);
    BAR;
    // phase 1: quadrant (0,1)
#pragma unroll
    for (int ks = 0; ks < 8; ++ks)
      b1[ks] = *(const long*)&Bcur[brow_b + 32 * BK + cofs[ks]];
    BAR;
    MMACC(acc01, a0, b1, sx0);
    BAR;
    // phase 2: quadrant (1,0); B units fully consumed -> stage kt+2 B
    if (kt + 2 < KT) { stageB(0, kt + 2, buf); stageB(64, kt + 2, buf); }
#pragma unroll
    for (int ks = 0; ks < 8; ++ks)
      a1[ks] = *(const long*)&Acur[arow_b + 32 * BK + cofs[ks]];
    LDSX(sx1, 1);
    BAR;
    MMACC(acc10, a1, b0, sx1);
    BAR;
    // phase 3: quadrant (1,1); A units fully consumed -> stage kt+2 A
    if (kt + 2 < KT) { stageA(0, kt + 2, buf); stageA(64, kt + 2, buf);
                       stageA(128, kt + 2, buf); stageA(192, kt + 2, buf); }
    BAR;
    MMACC(acc11, a1, b1, sx1);
    // drain-then-publish tile kt+1: own older 6 loads must land before barrier
    if (kt < KT - 2)       { asm volatile("s_waitcnt vmcnt(6)" ::: "memory"); }
    else if (kt == KT - 2) { asm volatile("s_waitcnt vmcnt(0)" ::: "memory"); }
    BAR;
    __builtin_amdgcn_sched_barrier(0);
  }

  // ---- epilogue: 32x32 C/D layout: col = l&31, row = (r&3)+8*(r>>2)+4*hi ----
#pragma unroll
  for (int mb = 0; mb < 2; ++mb) {
#pragma unroll
    for (int nb = 0; nb < 2; ++nb) {
      const f32x16 accv = mb == 0 ? (nb == 0 ? acc00 : acc01)
                                  : (nb == 0 ? acc10 : acc11);
      const int n = bcol + wc * 64 + nb * 32 + r32;
#pragma unroll
      for (int r = 0; r < 16; ++r) {
        const int m = brow + wr * 64 + mb * 32 + (r & 3) + 8 * (r >> 2) + 4 * hi;
        out[(size_t)(e * M_ + m) * N_ + n] = accv[r];
      }
    }
  }
}

extern "C" void kernel_launch(void* const* d_in, const int* in_sizes, int n_in,
                              void* d_out, int out_size, void* d_ws, size_t ws_size,
                              hipStream_t stream) {
  const float* x = (const float*)d_in[0];
  const float* wt = (const float*)d_in[1];
  float* out = (float*)d_out;

  unsigned char* ws = (unsigned char*)d_ws;
  unsigned char* qx = ws;                               // 64 MiB
  unsigned char* qw = ws + (size_t)E_ * M_ * K_;        // 32 MiB
  float* sx = (float*)(qw + (size_t)E_ * N_ * K_);      // 2 MiB
  float* sw = sx + (size_t)E_ * M_ * KB_;               // 8 KiB

  quant_x_kernel<<<dim3((E_ * M_ * KB_) / 8), dim3(256), 0, stream>>>(x, qx, sx);
  quant_w_kernel<<<dim3(E_ * NB128 * KB_), dim3(256), 0, stream>>>(wt, qw, sw);
  gemm_kernel<<<dim3(MT2 * NT2, E_), dim3(512), 0, stream>>>(qx, qw, sx, sw, out);
}